// Round 1
// baseline (146.392 us; speedup 1.0000x reference)
//
#include <hip/hip_runtime.h>
#include <math.h>

#define NROWS 8192
#define NCLS  1000
#define LAMBDA_P 0.01f

// ws layout: [0..1] float accumulators (ce_sum, penalty_sum); offset 16: int truth[NROWS]

__global__ void init_accum_k(float* accum) {
    accum[0] = 0.0f;
    accum[1] = 0.0f;
}

__global__ __launch_bounds__(256) void row_pass_k(const float* __restrict__ outputs,
                                                  const int* __restrict__ labels,
                                                  float* __restrict__ accum,
                                                  int* __restrict__ truth) {
    __shared__ __align__(16) float row[NCLS];
    __shared__ float sval[256];
    __shared__ int   sidx[256];
    __shared__ float ssum[256];

    const int r = blockIdx.x;
    const int t = threadIdx.x;
    const float* rp = outputs + (size_t)r * NCLS;

    // 1000 floats = 250 float4, 16B-aligned rows (4000 % 16 == 0)
    float4 v = make_float4(-INFINITY, -INFINITY, -INFINITY, -INFINITY);
    if (t < 250) {
        v = reinterpret_cast<const float4*>(rp)[t];
        reinterpret_cast<float4*>(row)[t] = v;
    }

    // local max/argmax with first-index tie-break
    int base = t * 4;
    float m = v.x; int mi = base;
    if (v.y > m) { m = v.y; mi = base + 1; }
    if (v.z > m) { m = v.z; mi = base + 2; }
    if (v.w > m) { m = v.w; mi = base + 3; }
    if (t >= 250) { m = -INFINITY; mi = NCLS; }

    sval[t] = m; sidx[t] = mi;
    __syncthreads();
    for (int s = 128; s > 0; s >>= 1) {
        if (t < s) {
            float ov = sval[t + s]; int oi = sidx[t + s];
            if (ov > sval[t] || (ov == sval[t] && oi < sidx[t])) {
                sval[t] = ov; sidx[t] = oi;
            }
        }
        __syncthreads();
    }
    const float rowmax = sval[0];
    const int   rowarg = sidx[0];
    __syncthreads();

    // sum of exp(x - rowmax); lanes t>=250 hold -INF components -> exp = 0
    float se = __expf(v.x - rowmax) + __expf(v.y - rowmax)
             + __expf(v.z - rowmax) + __expf(v.w - rowmax);
    ssum[t] = se;
    __syncthreads();
    for (int s = 128; s > 0; s >>= 1) {
        if (t < s) ssum[t] += ssum[t + s];
        __syncthreads();
    }

    if (t == 0) {
        int lab = labels[r];
        float xl = row[lab];
        float lse = rowmax + logf(ssum[0]);
        float ce = -(xl - lse);
        atomicAdd(&accum[0], ce);
        truth[r] = (rowarg == lab) ? 1 : 0;
    }
}

__global__ __launch_bounds__(256) void penalty_k(const float* __restrict__ conf,
                                                 const int* __restrict__ truth,
                                                 float* __restrict__ accum) {
    __shared__ float cj[256];
    __shared__ int   tj[256];
    __shared__ float part[256];

    const int t = threadIdx.x;
    const int i = blockIdx.x * 256 + t;
    const int j0 = blockIdx.y * 256;

    const float ci = conf[i];
    const int   ti = truth[i];
    cj[t] = conf[j0 + t];
    tj[t] = truth[j0 + t];
    __syncthreads();

    float acc = 0.0f;
    if (!ti) {
        #pragma unroll 8
        for (int k = 0; k < 256; ++k) {
            // tj[k] is wave-uniform (same k for all lanes) -> no divergence
            if (tj[k]) {
                float d = ci - cj[k];
                if (d > 0.0f) acc += d * d;
            }
        }
    }
    part[t] = acc;
    __syncthreads();
    for (int s = 128; s > 0; s >>= 1) {
        if (t < s) part[t] += part[t + s];
        __syncthreads();
    }
    if (t == 0) atomicAdd(&accum[1], part[0]);
}

__global__ void finalize_k(const float* __restrict__ accum, float* __restrict__ out) {
    out[0] = accum[0] * (1.0f / (float)NROWS) + LAMBDA_P * accum[1];
}

extern "C" void kernel_launch(void* const* d_in, const int* in_sizes, int n_in,
                              void* d_out, int out_size, void* d_ws, size_t ws_size,
                              hipStream_t stream) {
    const float* outputs = (const float*)d_in[0];
    const float* conf    = (const float*)d_in[1];
    const int*   labels  = (const int*)d_in[2];
    float* out   = (float*)d_out;
    float* accum = (float*)d_ws;
    int*   truth = (int*)((char*)d_ws + 16);

    init_accum_k<<<1, 1, 0, stream>>>(accum);
    row_pass_k<<<NROWS, 256, 0, stream>>>(outputs, labels, accum, truth);
    penalty_k<<<dim3(NROWS / 256, NROWS / 256), 256, 0, stream>>>(conf, truth, accum);
    finalize_k<<<1, 1, 0, stream>>>(accum, out);
}

// Round 2
// 37.623 us; speedup vs baseline: 3.8910x; 3.8910x over previous
//
#include <hip/hip_runtime.h>
#include <math.h>

#define NROWS 8192
#define NCLS  1000
#define NF4   250            // float4s per row (1000 floats)
#define LAMBDA_P 0.01f

#define CE_BLOCKS (NROWS / 4)   // 2048: 4 waves/block, 1 row/wave
#define PEN_TILE  256
#define PEN_GRID  (NROWS / PEN_TILE)   // 32

// ws layout: ce_part float[2048] @0 ; pen_part float[1024] @8192 ; truth u8[8192] @12288
// total 20480 B

__global__ __launch_bounds__(256) void row_pass_k(const float* __restrict__ outputs,
                                                  const int* __restrict__ labels,
                                                  float* __restrict__ ce_part,
                                                  unsigned char* __restrict__ truth) {
    __shared__ float sce[4];
    const int t    = threadIdx.x;
    const int lane = t & 63;
    const int wid  = t >> 6;
    const int r    = (blockIdx.x << 2) + wid;
    const float4* rp = reinterpret_cast<const float4*>(outputs) + (size_t)r * NF4;

    // 4 coalesced float4 loads per lane, all in flight at once
    float4 v[4];
#pragma unroll
    for (int k = 0; k < 4; ++k) {
        const int idx = lane + (k << 6);
        v[k] = (idx < NF4) ? rp[idx]
                           : make_float4(-INFINITY, -INFINITY, -INFINITY, -INFINITY);
    }
    const int lab = labels[r];

    // per-lane max/argmax; ascending global index order -> first-index tie-break
    float m = -INFINITY; int mi = 0x7fffffff;
#pragma unroll
    for (int k = 0; k < 4; ++k) {
        const int base = (lane + (k << 6)) << 2;
        if (v[k].x > m) { m = v[k].x; mi = base; }
        if (v[k].y > m) { m = v[k].y; mi = base + 1; }
        if (v[k].z > m) { m = v[k].z; mi = base + 2; }
        if (v[k].w > m) { m = v[k].w; mi = base + 3; }
    }
    // wave argmax butterfly (tie-break: smaller index)
#pragma unroll
    for (int off = 32; off > 0; off >>= 1) {
        const float om  = __shfl_xor(m, off, 64);
        const int   omi = __shfl_xor(mi, off, 64);
        if (om > m || (om == m && omi < mi)) { m = om; mi = omi; }
    }

    // x[label]: owning lane selects component (lk/lc/llane are wave-uniform), broadcast
    const int lab4  = lab >> 2;
    const int lk    = lab4 >> 6;
    const int llane = lab4 & 63;
    const int lc    = lab & 3;
    float4 vv = v[0];
    if (lk == 1) vv = v[1];
    if (lk == 2) vv = v[2];
    if (lk == 3) vv = v[3];
    float xs = vv.x;
    if (lc == 1) xs = vv.y;
    if (lc == 2) xs = vv.z;
    if (lc == 3) xs = vv.w;
    const float xl = __shfl(xs, llane, 64);

    // sum exp(x - m); padded entries are -INF -> exp() = 0
    float se = 0.0f;
#pragma unroll
    for (int k = 0; k < 4; ++k) {
        se += __expf(v[k].x - m) + __expf(v[k].y - m)
            + __expf(v[k].z - m) + __expf(v[k].w - m);
    }
#pragma unroll
    for (int off = 32; off > 0; off >>= 1) se += __shfl_xor(se, off, 64);

    if (lane == 0) {
        sce[wid] = (m + logf(se)) - xl;          // per-row CE contribution
        truth[r] = (mi == lab) ? 1u : 0u;
    }
    __syncthreads();
    if (t == 0) ce_part[blockIdx.x] = sce[0] + sce[1] + sce[2] + sce[3];
}

__global__ __launch_bounds__(256) void penalty_k(const float* __restrict__ conf,
                                                 const unsigned char* __restrict__ truth,
                                                 float* __restrict__ pen_part) {
    __shared__ float cj[PEN_TILE];
    __shared__ int   tj[PEN_TILE];
    __shared__ float part[256];

    const int t  = threadIdx.x;
    const int i  = blockIdx.x * PEN_TILE + t;
    const int j  = blockIdx.y * PEN_TILE + t;
    const int pidx = blockIdx.y * PEN_GRID + blockIdx.x;

    const int tjv = truth[j];
    cj[t] = conf[j];
    tj[t] = tjv;

    // skip j-tiles containing no correct samples (the common case: ~0.1% correct)
    if (__syncthreads_or(tjv) == 0) {
        if (t == 0) pen_part[pidx] = 0.0f;
        return;
    }

    const float ci = conf[i];
    const int   ti = truth[i];
    float acc = 0.0f;
    if (!ti) {
        for (int k = 0; k < PEN_TILE; ++k) {
            if (tj[k]) {                       // wave-uniform branch
                const float d = ci - cj[k];
                if (d > 0.0f) acc += d * d;
            }
        }
    }
    part[t] = acc;
    __syncthreads();
    for (int s = 128; s > 0; s >>= 1) {
        if (t < s) part[t] += part[t + s];
        __syncthreads();
    }
    if (t == 0) pen_part[pidx] = part[0];
}

__global__ __launch_bounds__(256) void finalize_k(const float* __restrict__ ce_part,
                                                  const float* __restrict__ pen_part,
                                                  float* __restrict__ out) {
    __shared__ float s1[4], s2[4];
    const int t = threadIdx.x;
    const int lane = t & 63, wid = t >> 6;
    float ce = 0.0f, pe = 0.0f;
    for (int i = t; i < CE_BLOCKS; i += 256) ce += ce_part[i];
    for (int i = t; i < PEN_GRID * PEN_GRID; i += 256) pe += pen_part[i];
#pragma unroll
    for (int off = 32; off > 0; off >>= 1) {
        ce += __shfl_xor(ce, off, 64);
        pe += __shfl_xor(pe, off, 64);
    }
    if (lane == 0) { s1[wid] = ce; s2[wid] = pe; }
    __syncthreads();
    if (t == 0) {
        out[0] = (s1[0] + s1[1] + s1[2] + s1[3]) * (1.0f / (float)NROWS)
               + LAMBDA_P * (s2[0] + s2[1] + s2[2] + s2[3]);
    }
}

extern "C" void kernel_launch(void* const* d_in, const int* in_sizes, int n_in,
                              void* d_out, int out_size, void* d_ws, size_t ws_size,
                              hipStream_t stream) {
    const float* outputs = (const float*)d_in[0];
    const float* conf    = (const float*)d_in[1];
    const int*   labels  = (const int*)d_in[2];
    float* out = (float*)d_out;

    float*         ce_part  = (float*)d_ws;
    float*         pen_part = (float*)((char*)d_ws + 8192);
    unsigned char* truth    = (unsigned char*)((char*)d_ws + 12288);

    row_pass_k<<<CE_BLOCKS, 256, 0, stream>>>(outputs, labels, ce_part, truth);
    penalty_k<<<dim3(PEN_GRID, PEN_GRID), 256, 0, stream>>>(conf, truth, pen_part);
    finalize_k<<<1, 256, 0, stream>>>(ce_part, pen_part, out);
}

// Round 3
// 25.822 us; speedup vs baseline: 5.6694x; 1.4570x over previous
//
#include <hip/hip_runtime.h>
#include <math.h>

#define NROWS 8192
#define NCLS  1000
#define NF4   250            // float4s per row (1000 floats)
#define LAMBDA_P 0.01f

#define CE_BLOCKS (NROWS / 4)   // 2048 blocks, 4 waves/block, 1 row/wave
#define PEN_BLOCKS 32           // 256 threads each -> 8192 threads, 1 i per thread

// ws layout:
//   ce_part  float[2048]  @ 0      (8192 B)
//   ce_sub   float[32]    @ 8192
//   pen_sub  float[32]    @ 8320
//   counter  int          @ 8448
//   truth    u8[8192]     @ 8704
// total 16896 B

__global__ __launch_bounds__(256) void row_pass_k(const float* __restrict__ outputs,
                                                  const int* __restrict__ labels,
                                                  float* __restrict__ ce_part,
                                                  unsigned char* __restrict__ truth,
                                                  int* __restrict__ counter) {
    __shared__ float sce[4];
    const int t    = threadIdx.x;
    const int lane = t & 63;
    const int wid  = t >> 6;
    const int r    = (blockIdx.x << 2) + wid;
    if (blockIdx.x == 0 && t == 0) *counter = 0;   // reset for fused finalize
    const float4* rp = reinterpret_cast<const float4*>(outputs) + (size_t)r * NF4;

    float4 v[4];
#pragma unroll
    for (int k = 0; k < 4; ++k) {
        const int idx = lane + (k << 6);
        v[k] = (idx < NF4) ? rp[idx]
                           : make_float4(-INFINITY, -INFINITY, -INFINITY, -INFINITY);
    }
    const int lab = labels[r];

    float m = -INFINITY; int mi = 0x7fffffff;
#pragma unroll
    for (int k = 0; k < 4; ++k) {
        const int base = (lane + (k << 6)) << 2;
        if (v[k].x > m) { m = v[k].x; mi = base; }
        if (v[k].y > m) { m = v[k].y; mi = base + 1; }
        if (v[k].z > m) { m = v[k].z; mi = base + 2; }
        if (v[k].w > m) { m = v[k].w; mi = base + 3; }
    }
#pragma unroll
    for (int off = 32; off > 0; off >>= 1) {
        const float om  = __shfl_xor(m, off, 64);
        const int   omi = __shfl_xor(mi, off, 64);
        if (om > m || (om == m && omi < mi)) { m = om; mi = omi; }
    }

    const int lab4  = lab >> 2;
    const int lk    = lab4 >> 6;
    const int llane = lab4 & 63;
    const int lc    = lab & 3;
    float4 vv = v[0];
    if (lk == 1) vv = v[1];
    if (lk == 2) vv = v[2];
    if (lk == 3) vv = v[3];
    float xs = vv.x;
    if (lc == 1) xs = vv.y;
    if (lc == 2) xs = vv.z;
    if (lc == 3) xs = vv.w;
    const float xl = __shfl(xs, llane, 64);

    float se = 0.0f;
#pragma unroll
    for (int k = 0; k < 4; ++k) {
        se += __expf(v[k].x - m) + __expf(v[k].y - m)
            + __expf(v[k].z - m) + __expf(v[k].w - m);
    }
#pragma unroll
    for (int off = 32; off > 0; off >>= 1) se += __shfl_xor(se, off, 64);

    if (lane == 0) {
        sce[wid] = (m + logf(se)) - xl;
        truth[r] = (mi == lab) ? 1u : 0u;
    }
    __syncthreads();
    if (t == 0) ce_part[blockIdx.x] = sce[0] + sce[1] + sce[2] + sce[3];
}

// Fused penalty + final combine. Exploits sparsity: only K ~ N/1000 rows are
// "correct"; each block builds the ordered compact list of correct confidences
// (deterministic ascending-j order), then each thread does a K-length inner loop.
__global__ __launch_bounds__(256) void penalty_fin_k(const float* __restrict__ conf,
                                                     const unsigned char* __restrict__ truth,
                                                     const float* __restrict__ ce_part,
                                                     float* __restrict__ ce_sub,
                                                     float* __restrict__ pen_sub,
                                                     int* __restrict__ counter,
                                                     float* __restrict__ out) {
    __shared__ float cconf[NROWS];     // worst-case compact list (32 KB)
    __shared__ int   wsum[4];
    __shared__ float sred[4];
    __shared__ float cred[1];
    __shared__ int   sK;
    __shared__ int   isLast;

    const int t    = threadIdx.x;
    const int lane = t & 63;
    const int wid  = t >> 6;
    const int b    = blockIdx.x;

    // ---- deterministic compaction of correct set (each block redundantly) ----
    // thread t scans truth[t*32 .. t*32+32)
    const uint* tru32 = reinterpret_cast<const uint*>(truth);
    uint words[8];
#pragma unroll
    for (int q = 0; q < 8; ++q) words[q] = tru32[t * 8 + q];
    int cnt = 0;
#pragma unroll
    for (int q = 0; q < 8; ++q) {
        uint w = words[q];
        cnt += (w & 0xffu ? 1 : 0) + ((w >> 8) & 0xffu ? 1 : 0)
             + ((w >> 16) & 0xffu ? 1 : 0) + ((w >> 24) & 0xffu ? 1 : 0);
    }
    // inclusive scan within wave
    int inc = cnt;
#pragma unroll
    for (int d = 1; d < 64; d <<= 1) {
        int n = __shfl_up(inc, d, 64);
        if (lane >= d) inc += n;
    }
    if (lane == 63) wsum[wid] = inc;
    __syncthreads();
    int woff = 0;
    for (int w = 0; w < wid; ++w) woff += wsum[w];
    int slot = woff + inc - cnt;           // exclusive prefix
    if (t == 255) sK = woff + inc;
    // ordered writes (ascending j)
#pragma unroll
    for (int q = 0; q < 8; ++q) {
        uint w = words[q];
#pragma unroll
        for (int byte = 0; byte < 4; ++byte) {
            if ((w >> (byte * 8)) & 0xffu) {
                cconf[slot++] = conf[t * 32 + q * 4 + byte];
            }
        }
    }
    __syncthreads();
    const int K = sK;

    // ---- penalty: one i per thread, inner loop over K correct entries ----
    const int i = b * 256 + t;
    const float ci = conf[i];
    float acc = 0.0f;
    if (!truth[i]) {
        for (int s = 0; s < K; ++s) {
            const float d = ci - cconf[s];
            if (d > 0.0f) acc += d * d;
        }
    }
#pragma unroll
    for (int off = 32; off > 0; off >>= 1) acc += __shfl_xor(acc, off, 64);
    if (lane == 0) sred[wid] = acc;

    // ---- this block's ce_part slice (64 entries) ----
    float ce = (t < 64) ? ce_part[b * 64 + t] : 0.0f;
    if (wid == 0) {
#pragma unroll
        for (int off = 32; off > 0; off >>= 1) ce += __shfl_xor(ce, off, 64);
        if (lane == 0) cred[0] = ce;
    }
    __syncthreads();
    if (t == 0) {
        pen_sub[b] = sred[0] + sred[1] + sred[2] + sred[3];
        ce_sub[b]  = cred[0];
        __threadfence();
        int c = atomicAdd(counter, 1);
        isLast = (c == PEN_BLOCKS - 1) ? 1 : 0;
    }
    __syncthreads();

    // ---- last block does the final 32-way combine ----
    if (isLast && wid == 0) {
        __threadfence();
        float cs = (lane < PEN_BLOCKS) ? ce_sub[lane]  : 0.0f;
        float ps = (lane < PEN_BLOCKS) ? pen_sub[lane] : 0.0f;
#pragma unroll
        for (int off = 32; off > 0; off >>= 1) {
            cs += __shfl_xor(cs, off, 64);
            ps += __shfl_xor(ps, off, 64);
        }
        if (lane == 0) out[0] = cs * (1.0f / (float)NROWS) + LAMBDA_P * ps;
    }
}

extern "C" void kernel_launch(void* const* d_in, const int* in_sizes, int n_in,
                              void* d_out, int out_size, void* d_ws, size_t ws_size,
                              hipStream_t stream) {
    const float* outputs = (const float*)d_in[0];
    const float* conf    = (const float*)d_in[1];
    const int*   labels  = (const int*)d_in[2];
    float* out = (float*)d_out;

    float*         ce_part = (float*)d_ws;
    float*         ce_sub  = (float*)((char*)d_ws + 8192);
    float*         pen_sub = (float*)((char*)d_ws + 8320);
    int*           counter = (int*)((char*)d_ws + 8448);
    unsigned char* truth   = (unsigned char*)((char*)d_ws + 8704);

    row_pass_k<<<CE_BLOCKS, 256, 0, stream>>>(outputs, labels, ce_part, truth, counter);
    penalty_fin_k<<<PEN_BLOCKS, 256, 0, stream>>>(conf, truth, ce_part,
                                                  ce_sub, pen_sub, counter, out);
}